// Round 1
// 597.911 us; speedup vs baseline: 1.2678x; 1.2678x over previous
//
#include <hip/hip_runtime.h>

// GraphSAGE 3-layer inference — R6.
//  * GEMM rewritten: double-buffered LDS staging via global_load_lds (width-16
//    async DMA, no VGPR cost -> loads actually stay in flight; the R5 register
//    prefetch ring was collapsed by the compiler to VGPR_Count=100 and ran
//    latency-bound at 15% HBM). Minimum 2-phase schedule: stage(t+1) -> ds_read
//    + MFMA on buf(t) -> one __syncthreads (vmcnt/lgkm drain) per K-step.
//    Tile 128x128, BK=64, 4 waves, 64KB LDS -> 2 blocks/CU.
//  * Gather / final_out / CSR build unchanged.

#define NN 100000
#define NE 800000
#define MPAD 100096   // 782 * 128

typedef __attribute__((ext_vector_type(8))) short short8;
typedef __attribute__((ext_vector_type(4))) float floatx4;

__device__ __forceinline__ float bf2f(unsigned short u) {
    unsigned int x = ((unsigned int)u) << 16;
    return __builtin_bit_cast(float, x);
}
__device__ __forceinline__ unsigned short f2bf(float f) {
    unsigned int x = __builtin_bit_cast(unsigned int, f);
    x += 0x7fffu + ((x >> 16) & 1u);   // round-to-nearest-even
    return (unsigned short)(x >> 16);
}

// async global->LDS, 16B per lane. LDS dest must be wave-uniform base; HW
// writes base + lane*16. Global src is per-lane.
__device__ __forceinline__ void gl_lds16(const unsigned short* g, unsigned short* l) {
    __builtin_amdgcn_global_load_lds(
        (const __attribute__((address_space(1))) unsigned int*)g,
        (__attribute__((address_space(3))) unsigned int*)l,
        16, 0, 0);
}

// ---------------- CSR build ----------------
__global__ void degi_kernel(const int* __restrict__ dst, int* __restrict__ deg) {
    int e = blockIdx.x * blockDim.x + threadIdx.x;
    if (e < NE) atomicAdd(&deg[dst[e]], 1);
}

// Exclusive scan of 102400 ints (int4 per thread, 25 iterations).
__global__ __launch_bounds__(1024) void scan_kernel(const int4* __restrict__ deg4,
                                                    int4* __restrict__ cur4) {
    __shared__ int wsum[16];
    __shared__ int carry_s;
    const int tid = threadIdx.x, lane = tid & 63, w = tid >> 6;
    if (tid == 0) carry_s = 0;
    __syncthreads();
    for (int base = 0; base < 25600; base += 1024) {
        int i = base + tid;
        int4 v = deg4[i];
        int t = v.x + v.y + v.z + v.w;
        int s = t;
        #pragma unroll
        for (int off = 1; off < 64; off <<= 1) {
            int u = __shfl_up(s, off, 64);
            if (lane >= off) s += u;
        }
        if (lane == 63) wsum[w] = s;
        __syncthreads();
        if (w == 0) {
            int ws_ = (lane < 16) ? wsum[lane] : 0;
            int t2 = ws_;
            #pragma unroll
            for (int off = 1; off < 16; off <<= 1) {
                int u = __shfl_up(t2, off, 64);
                if (lane >= off) t2 += u;
            }
            if (lane < 16) wsum[lane] = t2 - ws_;
        }
        __syncthreads();
        int excl = carry_s + wsum[w] + (s - t);
        int4 o;
        o.x = excl; o.y = o.x + v.x; o.z = o.y + v.y; o.w = o.z + v.z;
        cur4[i] = o;
        __syncthreads();
        if (tid == 1023) carry_s = excl + t;
        __syncthreads();
    }
}

__global__ void scatter_kernel(const int* __restrict__ src, const int* __restrict__ dst,
                               int* __restrict__ cursor, int* __restrict__ nbr) {
    int e = blockIdx.x * blockDim.x + threadIdx.x;
    if (e < NE) {
        int pos = atomicAdd(&cursor[dst[e]], 1);
        nbr[pos] = src[e];
    }
}

// ---------------- casts / weight prep ----------------
__global__ void cast_x_kernel(const float4* __restrict__ x, unsigned short* __restrict__ H) {
    int gid = blockIdx.x * 256 + threadIdx.x;   // NN*64 float4 groups
    if (gid >= NN * 64) return;
    int row = gid >> 6, col = (gid & 63) * 4;
    float4 v = x[gid];
    ushort4 o;
    o.x = f2bf(v.x); o.y = f2bf(v.y); o.z = f2bf(v.z); o.w = f2bf(v.w);
    *(ushort4*)&H[(size_t)row * 512 + col] = o;
}

// Bt[n][k] = bf16( k<256 ? Ws[k][n] : Wn[k-256][n] ),  [256][512]
__global__ void wprep_kernel(const float* __restrict__ Ws, const float* __restrict__ Wn,
                             unsigned short* __restrict__ Bt) {
    int idx = blockIdx.x * 256 + threadIdx.x;
    if (idx >= 256 * 512) return;
    int n = idx >> 9, k = idx & 511;
    float v = (k < 256) ? Ws[(size_t)k * 256 + n] : Wn[(size_t)(k - 256) * 256 + n];
    Bt[idx] = f2bf(v);
}

// Bt3[n][k] (n<128, k<256): n<64 -> Ws3[k][n], else Wn3[k][n-64]; b3ext = [b3 | 0]
__global__ void wprep3_kernel(const float* __restrict__ Ws3, const float* __restrict__ Wn3,
                              const float* __restrict__ b3, unsigned short* __restrict__ Bt3,
                              float* __restrict__ b3ext) {
    int idx = blockIdx.x * 256 + threadIdx.x;
    if (idx < 128 * 256) {
        int n = idx >> 8, k = idx & 255;
        float v = (n < 64) ? Ws3[(size_t)k * 64 + n] : Wn3[(size_t)k * 64 + (n - 64)];
        Bt3[idx] = f2bf(v);
    }
    if (idx < 128) b3ext[idx] = (idx < 64) ? b3[idx] : 0.f;
}

// ---------------- pull-mean gather (bf16, half-wave per edge, 2x unroll) ----------------
__global__ __launch_bounds__(256) void gather_bf16(unsigned short* __restrict__ H,
                                                   const int* __restrict__ nbr,
                                                   const int* __restrict__ cursor,
                                                   const int* __restrict__ deg) {
    const int lane = threadIdx.x & 63;
    const int sub  = threadIdx.x >> 6;
    const int d = blockIdx.x * 4 + sub;
    if (d >= NN) return;
    const int dg = deg[d];
    const int end = cursor[d];
    const int start = end - dg;
    const int half = lane >> 5, l32 = lane & 31;
    float acc0[8] = {0.f, 0.f, 0.f, 0.f, 0.f, 0.f, 0.f, 0.f};
    float acc1[8] = {0.f, 0.f, 0.f, 0.f, 0.f, 0.f, 0.f, 0.f};
    int j = start + half;
    for (; j + 2 < end; j += 4) {
        int s0 = nbr[j], s1 = nbr[j + 2];
        short8 v0 = *(const short8*)&H[(size_t)s0 * 512 + l32 * 8];
        short8 v1 = *(const short8*)&H[(size_t)s1 * 512 + l32 * 8];
        #pragma unroll
        for (int i = 0; i < 8; ++i) acc0[i] += bf2f((unsigned short)v0[i]);
        #pragma unroll
        for (int i = 0; i < 8; ++i) acc1[i] += bf2f((unsigned short)v1[i]);
    }
    for (; j < end; j += 2) {
        int s0 = nbr[j];
        short8 v0 = *(const short8*)&H[(size_t)s0 * 512 + l32 * 8];
        #pragma unroll
        for (int i = 0; i < 8; ++i) acc0[i] += bf2f((unsigned short)v0[i]);
    }
    #pragma unroll
    for (int i = 0; i < 8; ++i) acc0[i] += acc1[i];
    #pragma unroll
    for (int i = 0; i < 8; ++i) acc0[i] += __shfl_xor(acc0[i], 32, 64);
    if (half == 0) {
        const float inv = 1.0f / fmaxf((float)dg, 1.0f);
        short8 o;
        #pragma unroll
        for (int i = 0; i < 8; ++i) o[i] = (short)f2bf(acc0[i] * inv);
        *(short8*)&H[(size_t)d * 512 + 256 + l32 * 8] = o;
    }
}

// ---------------- bf16 MFMA GEMM: global_load_lds double-buffered 2-phase ----------------
// C[128 x 128 per block] = A[., K] @ Bt^T + bias.
// A row stride 512 shorts (H fmt). Bt row stride = KT*64 shorts.
// KT = number of BK=64 K-steps (layer1/2: 8 -> K=512; layer3: 4 -> K=256).
// Per step, each of 4 waves stages its 32-row slice of A and B (8x 1KB DMA),
// then all waves ds_read fragments of buf(t) and run 32 MFMA; one
// __syncthreads (full vmcnt+lgkm drain) per step. Operands swapped in mfma
// so lane owns 4 consecutive output cols (same mapping as R5).
template <int KT, bool RELU>
__global__ __launch_bounds__(256, 2) void sage_mfma(const unsigned short* __restrict__ A,
                                                    const unsigned short* __restrict__ Bt,
                                                    const float* __restrict__ bias,
                                                    unsigned short* __restrict__ Cout, int ldc) {
    __shared__ unsigned short sm[2][2][128 * 64];   // [buf][A=0/B=1][row*64+col], 64 KiB
    constexpr int BSTR = KT * 64;                   // Bt row stride in shorts
    const int tid = threadIdx.x;
    const int lane = tid & 63;
    const int w = tid >> 6, wm = w >> 1, wn = w & 1;
    const int m0 = blockIdx.x * 128, n0 = blockIdx.y * 128;
    const int lr = lane & 15, lq = lane >> 4;

    // staging geometry: wave w owns rows [w*32, w*32+32) of both tiles.
    // lane l covers row +(l>>3), shorts (l&7)*8 .. +8 of the 64-short K-slab.
    const int srow = w * 32 + (lane >> 3);
    const int scol = (lane & 7) * 8;
    const unsigned short* gA = A  + (size_t)(m0 + srow) * 512  + scol;
    const unsigned short* gB = Bt + (size_t)(n0 + srow) * BSTR + scol;

    floatx4 acc[4][4] = {};

    // prologue: stage step 0 into buf 0
    {
        unsigned short* lA = &sm[0][0][(w * 32) * 64];
        unsigned short* lB = &sm[0][1][(w * 32) * 64];
        #pragma unroll
        for (int c = 0; c < 4; ++c) {
            gl_lds16(gA + (size_t)c * 8 * 512,  lA + c * 8 * 64);
            gl_lds16(gB + (size_t)c * 8 * BSTR, lB + c * 8 * 64);
        }
    }
    __syncthreads();

    #pragma unroll
    for (int t = 0; t < KT; ++t) {
        const int buf = t & 1;
        // phase 1: issue next step's DMA into the other buffer
        if (t + 1 < KT) {
            unsigned short* lA = &sm[buf ^ 1][0][(w * 32) * 64];
            unsigned short* lB = &sm[buf ^ 1][1][(w * 32) * 64];
            const unsigned short* pA = gA + (size_t)(t + 1) * 64;
            const unsigned short* pB = gB + (size_t)(t + 1) * 64;
            #pragma unroll
            for (int c = 0; c < 4; ++c) {
                gl_lds16(pA + (size_t)c * 8 * 512,  lA + c * 8 * 64);
                gl_lds16(pB + (size_t)c * 8 * BSTR, lB + c * 8 * 64);
            }
        }
        // phase 2: consume current buffer
        const unsigned short* bA = &sm[buf][0][0];
        const unsigned short* bB = &sm[buf][1][0];
        #pragma unroll
        for (int ks = 0; ks < 2; ++ks) {
            short8 af[4], bf[4];
            #pragma unroll
            for (int mi = 0; mi < 4; ++mi)
                af[mi] = *(const short8*)&bA[(wm * 64 + mi * 16 + lr) * 64 + ks * 32 + lq * 8];
            #pragma unroll
            for (int ni = 0; ni < 4; ++ni)
                bf[ni] = *(const short8*)&bB[(wn * 64 + ni * 16 + lr) * 64 + ks * 32 + lq * 8];
            #pragma unroll
            for (int mi = 0; mi < 4; ++mi)
                #pragma unroll
                for (int ni = 0; ni < 4; ++ni)
                    acc[mi][ni] = __builtin_amdgcn_mfma_f32_16x16x32_bf16(bf[ni], af[mi],
                                                                          acc[mi][ni], 0, 0, 0);
        }
        __syncthreads();   // drains this step's DMA (vmcnt) + all ds_reads
    }

    // Epilogue: bias + (relu) + bf16 -> LDS slab (aliases sm) -> coalesced 16B stores.
    unsigned short* slab = &sm[0][0][0];   // needs 128*136 shorts = 34816 B <= 64 KiB
    #pragma unroll
    for (int mi = 0; mi < 4; ++mi) {
        const int rl = wm * 64 + mi * 16 + lr;
        #pragma unroll
        for (int ni = 0; ni < 4; ++ni) {
            const int cl = wn * 64 + ni * 16 + lq * 4;
            const float4 bv = *(const float4*)&bias[n0 + cl];
            float v0 = acc[mi][ni][0] + bv.x;
            float v1 = acc[mi][ni][1] + bv.y;
            float v2 = acc[mi][ni][2] + bv.z;
            float v3 = acc[mi][ni][3] + bv.w;
            if (RELU) {
                v0 = fmaxf(v0, 0.f); v1 = fmaxf(v1, 0.f);
                v2 = fmaxf(v2, 0.f); v3 = fmaxf(v3, 0.f);
            }
            ushort4 o;
            o.x = f2bf(v0); o.y = f2bf(v1); o.z = f2bf(v2); o.w = f2bf(v3);
            *(ushort4*)&slab[rl * 136 + cl] = o;
        }
    }
    __syncthreads();
    #pragma unroll
    for (int it = 0; it < 8; ++it) {
        int idx = it * 256 + tid;
        int row = idx >> 4, c8 = (idx & 15) * 8;
        if (m0 + row < NN) {
            short8 v = *(const short8*)&slab[row * 136 + c8];
            *(short8*)&Cout[(size_t)(m0 + row) * ldc + n0 + c8] = v;
        }
    }
}

// ---------------- layer-3 finalize: out = S + mean_agg(P), 2x unroll ----------------
__global__ __launch_bounds__(256) void final_out(const unsigned short* __restrict__ T,
                                                 const int* __restrict__ nbr,
                                                 const int* __restrict__ cursor,
                                                 const int* __restrict__ deg,
                                                 float* __restrict__ out) {
    const int lane = threadIdx.x & 63;
    const int sub  = threadIdx.x >> 6;
    const int d = blockIdx.x * 4 + sub;
    if (d >= NN) return;
    const int dg = deg[d];
    const int end = cursor[d];
    float a0 = 0.f, a1 = 0.f;
    int j = end - dg;
    for (; j + 1 < end; j += 2) {
        int s0 = nbr[j], s1 = nbr[j + 1];
        float u0 = bf2f(T[(size_t)s0 * 128 + 64 + lane]);
        float u1 = bf2f(T[(size_t)s1 * 128 + 64 + lane]);
        a0 += u0; a1 += u1;
    }
    if (j < end) a0 += bf2f(T[(size_t)nbr[j] * 128 + 64 + lane]);
    const float inv = 1.0f / fmaxf((float)dg, 1.0f);
    const float sv = bf2f(T[(size_t)d * 128 + lane]);
    out[(size_t)d * 64 + lane] = sv + (a0 + a1) * inv;
}

extern "C" void kernel_launch(void* const* d_in, const int* in_sizes, int n_in,
                              void* d_out, int out_size, void* d_ws, size_t ws_size,
                              hipStream_t stream) {
    const float* x   = (const float*)d_in[0];
    const int*   src = (const int*)d_in[1];
    const int*   dst = (const int*)d_in[2];
    const float* Ws1 = (const float*)d_in[3];
    const float* Wn1 = (const float*)d_in[4];
    const float* b1  = (const float*)d_in[5];
    const float* Ws2 = (const float*)d_in[6];
    const float* Wn2 = (const float*)d_in[7];
    const float* b2  = (const float*)d_in[8];
    const float* Ws3 = (const float*)d_in[9];
    const float* Wn3 = (const float*)d_in[10];
    const float* b3  = (const float*)d_in[11];

    unsigned short* H1  = (unsigned short*)d_ws;
    unsigned short* H2  = H1  + (size_t)MPAD * 512;
    unsigned short* T   = H2  + (size_t)MPAD * 512;
    unsigned short* Bt1 = T   + (size_t)MPAD * 128;
    unsigned short* Bt2 = Bt1 + 256 * 512;
    unsigned short* Bt3 = Bt2 + 256 * 512;
    float* b3ext = (float*)(Bt3 + 128 * 256);
    int* deg    = (int*)(b3ext + 128);
    int* cursor = deg + 102400;
    int* nbr    = cursor + 102400;

    // CSR build (graph shared by all layers); pad region zeroed for int4 scan.
    hipMemsetAsync(deg, 0, 102400 * sizeof(int), stream);
    degi_kernel<<<(NE + 255) / 256, 256, 0, stream>>>(dst, deg);
    scan_kernel<<<1, 1024, 0, stream>>>((const int4*)deg, (int4*)cursor);
    scatter_kernel<<<(NE + 255) / 256, 256, 0, stream>>>(src, dst, cursor, nbr);
    // cursor[d] = end offset; bucket d = nbr[end-deg .. end)

    // bf16 prep
    cast_x_kernel<<<(NN * 64 + 255) / 256, 256, 0, stream>>>((const float4*)x, H1);
    wprep_kernel<<<512, 256, 0, stream>>>(Ws1, Wn1, Bt1);
    wprep_kernel<<<512, 256, 0, stream>>>(Ws2, Wn2, Bt2);
    wprep3_kernel<<<128, 256, 0, stream>>>(Ws3, Wn3, b3, Bt3, b3ext);

    const int gatherBlocks = (NN + 3) / 4;
    const dim3 g2(MPAD / 128, 2), g1(MPAD / 128, 1);

    // layer 1: H1 -> H2(left)
    gather_bf16<<<gatherBlocks, 256, 0, stream>>>(H1, nbr, cursor, deg);
    sage_mfma<8, true><<<g2, 256, 0, stream>>>(H1, Bt1, b1, H2, 512);

    // layer 2: H2 -> H1(left)
    gather_bf16<<<gatherBlocks, 256, 0, stream>>>(H2, nbr, cursor, deg);
    sage_mfma<8, true><<<g2, 256, 0, stream>>>(H2, Bt2, b2, H1, 512);

    // layer 3: T = [H1@Ws3+b3 | H1@Wn3] (K=256), then out = S + agg(P)
    sage_mfma<4, false><<<g1, 256, 0, stream>>>(H1, Bt3, b3ext, T, 128);
    final_out<<<gatherBlocks, 256, 0, stream>>>(T, nbr, cursor, deg, (float*)d_out);
}

// Round 2
// 564.703 us; speedup vs baseline: 1.3424x; 1.0588x over previous
//
#include <hip/hip_runtime.h>

// GraphSAGE 3-layer inference — R7.
//  * final_out restructured: 4 lane-groups x 16 lanes (ushort4 row reads),
//    2x unroll -> 8 edge rows (1KB) in flight per wave (was 2 x 128B).
//    Cross-group combine via shfl_xor(16/32); group 0 writes float4.
//  * gather_bf16 restructured: full wave covers the 512B row at 8B/lane,
//    8/4/1 unroll tiers -> up to 8 rows (4KB) in flight per wave; tiers
//    engage at deg>=8 / deg>=4 instead of deg>=16 / deg>=8.
//  * GEMM (global_load_lds 2-phase double-buffer), CSR build, prep unchanged.

#define NN 100000
#define NE 800000
#define MPAD 100096   // 782 * 128

typedef __attribute__((ext_vector_type(8))) short short8;
typedef __attribute__((ext_vector_type(4))) float floatx4;

__device__ __forceinline__ float bf2f(unsigned short u) {
    unsigned int x = ((unsigned int)u) << 16;
    return __builtin_bit_cast(float, x);
}
__device__ __forceinline__ unsigned short f2bf(float f) {
    unsigned int x = __builtin_bit_cast(unsigned int, f);
    x += 0x7fffu + ((x >> 16) & 1u);   // round-to-nearest-even
    return (unsigned short)(x >> 16);
}

// async global->LDS, 16B per lane. LDS dest must be wave-uniform base; HW
// writes base + lane*16. Global src is per-lane.
__device__ __forceinline__ void gl_lds16(const unsigned short* g, unsigned short* l) {
    __builtin_amdgcn_global_load_lds(
        (const __attribute__((address_space(1))) unsigned int*)g,
        (__attribute__((address_space(3))) unsigned int*)l,
        16, 0, 0);
}

// ---------------- CSR build ----------------
__global__ void degi_kernel(const int* __restrict__ dst, int* __restrict__ deg) {
    int e = blockIdx.x * blockDim.x + threadIdx.x;
    if (e < NE) atomicAdd(&deg[dst[e]], 1);
}

// Exclusive scan of 102400 ints (int4 per thread, 25 iterations).
__global__ __launch_bounds__(1024) void scan_kernel(const int4* __restrict__ deg4,
                                                    int4* __restrict__ cur4) {
    __shared__ int wsum[16];
    __shared__ int carry_s;
    const int tid = threadIdx.x, lane = tid & 63, w = tid >> 6;
    if (tid == 0) carry_s = 0;
    __syncthreads();
    for (int base = 0; base < 25600; base += 1024) {
        int i = base + tid;
        int4 v = deg4[i];
        int t = v.x + v.y + v.z + v.w;
        int s = t;
        #pragma unroll
        for (int off = 1; off < 64; off <<= 1) {
            int u = __shfl_up(s, off, 64);
            if (lane >= off) s += u;
        }
        if (lane == 63) wsum[w] = s;
        __syncthreads();
        if (w == 0) {
            int ws_ = (lane < 16) ? wsum[lane] : 0;
            int t2 = ws_;
            #pragma unroll
            for (int off = 1; off < 16; off <<= 1) {
                int u = __shfl_up(t2, off, 64);
                if (lane >= off) t2 += u;
            }
            if (lane < 16) wsum[lane] = t2 - ws_;
        }
        __syncthreads();
        int excl = carry_s + wsum[w] + (s - t);
        int4 o;
        o.x = excl; o.y = o.x + v.x; o.z = o.y + v.y; o.w = o.z + v.z;
        cur4[i] = o;
        __syncthreads();
        if (tid == 1023) carry_s = excl + t;
        __syncthreads();
    }
}

__global__ void scatter_kernel(const int* __restrict__ src, const int* __restrict__ dst,
                               int* __restrict__ cursor, int* __restrict__ nbr) {
    int e = blockIdx.x * blockDim.x + threadIdx.x;
    if (e < NE) {
        int pos = atomicAdd(&cursor[dst[e]], 1);
        nbr[pos] = src[e];
    }
}

// ---------------- casts / weight prep ----------------
__global__ void cast_x_kernel(const float4* __restrict__ x, unsigned short* __restrict__ H) {
    int gid = blockIdx.x * 256 + threadIdx.x;   // NN*64 float4 groups
    if (gid >= NN * 64) return;
    int row = gid >> 6, col = (gid & 63) * 4;
    float4 v = x[gid];
    ushort4 o;
    o.x = f2bf(v.x); o.y = f2bf(v.y); o.z = f2bf(v.z); o.w = f2bf(v.w);
    *(ushort4*)&H[(size_t)row * 512 + col] = o;
}

// Bt[n][k] = bf16( k<256 ? Ws[k][n] : Wn[k-256][n] ),  [256][512]
__global__ void wprep_kernel(const float* __restrict__ Ws, const float* __restrict__ Wn,
                             unsigned short* __restrict__ Bt) {
    int idx = blockIdx.x * 256 + threadIdx.x;
    if (idx >= 256 * 512) return;
    int n = idx >> 9, k = idx & 511;
    float v = (k < 256) ? Ws[(size_t)k * 256 + n] : Wn[(size_t)(k - 256) * 256 + n];
    Bt[idx] = f2bf(v);
}

// Bt3[n][k] (n<128, k<256): n<64 -> Ws3[k][n], else Wn3[k][n-64]; b3ext = [b3 | 0]
__global__ void wprep3_kernel(const float* __restrict__ Ws3, const float* __restrict__ Wn3,
                              const float* __restrict__ b3, unsigned short* __restrict__ Bt3,
                              float* __restrict__ b3ext) {
    int idx = blockIdx.x * 256 + threadIdx.x;
    if (idx < 128 * 256) {
        int n = idx >> 8, k = idx & 255;
        float v = (n < 64) ? Ws3[(size_t)k * 64 + n] : Wn3[(size_t)k * 64 + (n - 64)];
        Bt3[idx] = f2bf(v);
    }
    if (idx < 128) b3ext[idx] = (idx < 64) ? b3[idx] : 0.f;
}

// ---------------- pull-mean gather: full wave per node, 8B/lane, 8/4/1 tiers ----------------
__global__ __launch_bounds__(256) void gather_bf16(unsigned short* __restrict__ H,
                                                   const int* __restrict__ nbr,
                                                   const int* __restrict__ cursor,
                                                   const int* __restrict__ deg) {
    const int lane = threadIdx.x & 63;
    const int sub  = threadIdx.x >> 6;
    const int d = blockIdx.x * 4 + sub;
    if (d >= NN) return;
    const int dg = deg[d];
    const int end = cursor[d];
    const int start = end - dg;
    const int co = lane * 4;          // shorts 4*lane .. +4 of the 256-short left half
    float acc[4] = {0.f, 0.f, 0.f, 0.f};

    int j = start;
    for (; j + 7 < end; j += 8) {     // 8 rows (4KB) in flight
        int s0 = nbr[j],     s1 = nbr[j + 1], s2 = nbr[j + 2], s3 = nbr[j + 3];
        int s4 = nbr[j + 4], s5 = nbr[j + 5], s6 = nbr[j + 6], s7 = nbr[j + 7];
        ushort4 v0 = *(const ushort4*)&H[(size_t)s0 * 512 + co];
        ushort4 v1 = *(const ushort4*)&H[(size_t)s1 * 512 + co];
        ushort4 v2 = *(const ushort4*)&H[(size_t)s2 * 512 + co];
        ushort4 v3 = *(const ushort4*)&H[(size_t)s3 * 512 + co];
        ushort4 v4 = *(const ushort4*)&H[(size_t)s4 * 512 + co];
        ushort4 v5 = *(const ushort4*)&H[(size_t)s5 * 512 + co];
        ushort4 v6 = *(const ushort4*)&H[(size_t)s6 * 512 + co];
        ushort4 v7 = *(const ushort4*)&H[(size_t)s7 * 512 + co];
        acc[0] += (bf2f(v0.x) + bf2f(v1.x)) + (bf2f(v2.x) + bf2f(v3.x))
                + (bf2f(v4.x) + bf2f(v5.x)) + (bf2f(v6.x) + bf2f(v7.x));
        acc[1] += (bf2f(v0.y) + bf2f(v1.y)) + (bf2f(v2.y) + bf2f(v3.y))
                + (bf2f(v4.y) + bf2f(v5.y)) + (bf2f(v6.y) + bf2f(v7.y));
        acc[2] += (bf2f(v0.z) + bf2f(v1.z)) + (bf2f(v2.z) + bf2f(v3.z))
                + (bf2f(v4.z) + bf2f(v5.z)) + (bf2f(v6.z) + bf2f(v7.z));
        acc[3] += (bf2f(v0.w) + bf2f(v1.w)) + (bf2f(v2.w) + bf2f(v3.w))
                + (bf2f(v4.w) + bf2f(v5.w)) + (bf2f(v6.w) + bf2f(v7.w));
    }
    for (; j + 3 < end; j += 4) {     // 4 rows in flight
        int s0 = nbr[j], s1 = nbr[j + 1], s2 = nbr[j + 2], s3 = nbr[j + 3];
        ushort4 v0 = *(const ushort4*)&H[(size_t)s0 * 512 + co];
        ushort4 v1 = *(const ushort4*)&H[(size_t)s1 * 512 + co];
        ushort4 v2 = *(const ushort4*)&H[(size_t)s2 * 512 + co];
        ushort4 v3 = *(const ushort4*)&H[(size_t)s3 * 512 + co];
        acc[0] += (bf2f(v0.x) + bf2f(v1.x)) + (bf2f(v2.x) + bf2f(v3.x));
        acc[1] += (bf2f(v0.y) + bf2f(v1.y)) + (bf2f(v2.y) + bf2f(v3.y));
        acc[2] += (bf2f(v0.z) + bf2f(v1.z)) + (bf2f(v2.z) + bf2f(v3.z));
        acc[3] += (bf2f(v0.w) + bf2f(v1.w)) + (bf2f(v2.w) + bf2f(v3.w));
    }
    for (; j < end; ++j) {
        int s0 = nbr[j];
        ushort4 v0 = *(const ushort4*)&H[(size_t)s0 * 512 + co];
        acc[0] += bf2f(v0.x); acc[1] += bf2f(v0.y);
        acc[2] += bf2f(v0.z); acc[3] += bf2f(v0.w);
    }

    const float inv = 1.0f / fmaxf((float)dg, 1.0f);
    ushort4 o;
    o.x = f2bf(acc[0] * inv); o.y = f2bf(acc[1] * inv);
    o.z = f2bf(acc[2] * inv); o.w = f2bf(acc[3] * inv);
    *(ushort4*)&H[(size_t)d * 512 + 256 + co] = o;
}

// ---------------- bf16 MFMA GEMM: global_load_lds double-buffered 2-phase ----------------
// C[128 x 128 per block] = A[., K] @ Bt^T + bias.
// A row stride 512 shorts (H fmt). Bt row stride = KT*64 shorts.
// KT = number of BK=64 K-steps (layer1/2: 8 -> K=512; layer3: 4 -> K=256).
template <int KT, bool RELU>
__global__ __launch_bounds__(256, 2) void sage_mfma(const unsigned short* __restrict__ A,
                                                    const unsigned short* __restrict__ Bt,
                                                    const float* __restrict__ bias,
                                                    unsigned short* __restrict__ Cout, int ldc) {
    __shared__ unsigned short sm[2][2][128 * 64];   // [buf][A=0/B=1][row*64+col], 64 KiB
    constexpr int BSTR = KT * 64;                   // Bt row stride in shorts
    const int tid = threadIdx.x;
    const int lane = tid & 63;
    const int w = tid >> 6, wm = w >> 1, wn = w & 1;
    const int m0 = blockIdx.x * 128, n0 = blockIdx.y * 128;
    const int lr = lane & 15, lq = lane >> 4;

    // staging geometry: wave w owns rows [w*32, w*32+32) of both tiles.
    const int srow = w * 32 + (lane >> 3);
    const int scol = (lane & 7) * 8;
    const unsigned short* gA = A  + (size_t)(m0 + srow) * 512  + scol;
    const unsigned short* gB = Bt + (size_t)(n0 + srow) * BSTR + scol;

    floatx4 acc[4][4] = {};

    // prologue: stage step 0 into buf 0
    {
        unsigned short* lA = &sm[0][0][(w * 32) * 64];
        unsigned short* lB = &sm[0][1][(w * 32) * 64];
        #pragma unroll
        for (int c = 0; c < 4; ++c) {
            gl_lds16(gA + (size_t)c * 8 * 512,  lA + c * 8 * 64);
            gl_lds16(gB + (size_t)c * 8 * BSTR, lB + c * 8 * 64);
        }
    }
    __syncthreads();

    #pragma unroll
    for (int t = 0; t < KT; ++t) {
        const int buf = t & 1;
        // phase 1: issue next step's DMA into the other buffer
        if (t + 1 < KT) {
            unsigned short* lA = &sm[buf ^ 1][0][(w * 32) * 64];
            unsigned short* lB = &sm[buf ^ 1][1][(w * 32) * 64];
            const unsigned short* pA = gA + (size_t)(t + 1) * 64;
            const unsigned short* pB = gB + (size_t)(t + 1) * 64;
            #pragma unroll
            for (int c = 0; c < 4; ++c) {
                gl_lds16(pA + (size_t)c * 8 * 512,  lA + c * 8 * 64);
                gl_lds16(pB + (size_t)c * 8 * BSTR, lB + c * 8 * 64);
            }
        }
        // phase 2: consume current buffer
        const unsigned short* bA = &sm[buf][0][0];
        const unsigned short* bB = &sm[buf][1][0];
        #pragma unroll
        for (int ks = 0; ks < 2; ++ks) {
            short8 af[4], bf[4];
            #pragma unroll
            for (int mi = 0; mi < 4; ++mi)
                af[mi] = *(const short8*)&bA[(wm * 64 + mi * 16 + lr) * 64 + ks * 32 + lq * 8];
            #pragma unroll
            for (int ni = 0; ni < 4; ++ni)
                bf[ni] = *(const short8*)&bB[(wn * 64 + ni * 16 + lr) * 64 + ks * 32 + lq * 8];
            #pragma unroll
            for (int mi = 0; mi < 4; ++mi)
                #pragma unroll
                for (int ni = 0; ni < 4; ++ni)
                    acc[mi][ni] = __builtin_amdgcn_mfma_f32_16x16x32_bf16(bf[ni], af[mi],
                                                                          acc[mi][ni], 0, 0, 0);
        }
        __syncthreads();   // drains this step's DMA (vmcnt) + all ds_reads
    }

    // Epilogue: bias + (relu) + bf16 -> LDS slab (aliases sm) -> coalesced 16B stores.
    unsigned short* slab = &sm[0][0][0];   // 128*136 shorts = 34816 B <= 64 KiB
    #pragma unroll
    for (int mi = 0; mi < 4; ++mi) {
        const int rl = wm * 64 + mi * 16 + lr;
        #pragma unroll
        for (int ni = 0; ni < 4; ++ni) {
            const int cl = wn * 64 + ni * 16 + lq * 4;
            const float4 bv = *(const float4*)&bias[n0 + cl];
            float v0 = acc[mi][ni][0] + bv.x;
            float v1 = acc[mi][ni][1] + bv.y;
            float v2 = acc[mi][ni][2] + bv.z;
            float v3 = acc[mi][ni][3] + bv.w;
            if (RELU) {
                v0 = fmaxf(v0, 0.f); v1 = fmaxf(v1, 0.f);
                v2 = fmaxf(v2, 0.f); v3 = fmaxf(v3, 0.f);
            }
            ushort4 o;
            o.x = f2bf(v0); o.y = f2bf(v1); o.z = f2bf(v2); o.w = f2bf(v3);
            *(ushort4*)&slab[rl * 136 + cl] = o;
        }
    }
    __syncthreads();
    #pragma unroll
    for (int it = 0; it < 8; ++it) {
        int idx = it * 256 + tid;
        int row = idx >> 4, c8 = (idx & 15) * 8;
        if (m0 + row < NN) {
            short8 v = *(const short8*)&slab[row * 136 + c8];
            *(short8*)&Cout[(size_t)(m0 + row) * ldc + n0 + c8] = v;
        }
    }
}

// ---------------- layer-3 finalize: out = S + mean_agg(P) ----------------
// 4 lane-groups x 16 lanes; group g handles edges j == g (mod 4); each row
// read as ushort4 (16 lanes x 8B = 128B). 2x unroll -> 8 rows in flight.
__global__ __launch_bounds__(256) void final_out(const unsigned short* __restrict__ T,
                                                 const int* __restrict__ nbr,
                                                 const int* __restrict__ cursor,
                                                 const int* __restrict__ deg,
                                                 float* __restrict__ out) {
    const int lane = threadIdx.x & 63;
    const int sub  = threadIdx.x >> 6;
    const int d = blockIdx.x * 4 + sub;
    if (d >= NN) return;
    const int g  = lane >> 4;         // edge group 0..3
    const int li = lane & 15;         // column li*4 .. +4
    const int dg = deg[d];
    const int end = cursor[d];
    const int start = end - dg;
    const int co = li * 4;

    // self row (same addresses in all 4 groups -> broadcast), issued early
    ushort4 sv = *(const ushort4*)&T[(size_t)d * 128 + co];

    float acc[4] = {0.f, 0.f, 0.f, 0.f};
    int j = start + g;
    for (; j + 4 < end; j += 8) {     // 2 rows in flight per group (8 per wave)
        int s0 = nbr[j], s1 = nbr[j + 4];
        ushort4 v0 = *(const ushort4*)&T[(size_t)s0 * 128 + 64 + co];
        ushort4 v1 = *(const ushort4*)&T[(size_t)s1 * 128 + 64 + co];
        acc[0] += bf2f(v0.x) + bf2f(v1.x);
        acc[1] += bf2f(v0.y) + bf2f(v1.y);
        acc[2] += bf2f(v0.z) + bf2f(v1.z);
        acc[3] += bf2f(v0.w) + bf2f(v1.w);
    }
    for (; j < end; j += 4) {
        int s0 = nbr[j];
        ushort4 v0 = *(const ushort4*)&T[(size_t)s0 * 128 + 64 + co];
        acc[0] += bf2f(v0.x); acc[1] += bf2f(v0.y);
        acc[2] += bf2f(v0.z); acc[3] += bf2f(v0.w);
    }

    // combine the 4 groups: lanes differing in bits 4/5 hold same columns
    #pragma unroll
    for (int i = 0; i < 4; ++i) {
        acc[i] += __shfl_xor(acc[i], 16, 64);
        acc[i] += __shfl_xor(acc[i], 32, 64);
    }

    if (g == 0) {
        const float inv = 1.0f / fmaxf((float)dg, 1.0f);
        float4 o;
        o.x = bf2f(sv.x) + acc[0] * inv;
        o.y = bf2f(sv.y) + acc[1] * inv;
        o.z = bf2f(sv.z) + acc[2] * inv;
        o.w = bf2f(sv.w) + acc[3] * inv;
        *(float4*)&out[(size_t)d * 64 + co] = o;
    }
}

extern "C" void kernel_launch(void* const* d_in, const int* in_sizes, int n_in,
                              void* d_out, int out_size, void* d_ws, size_t ws_size,
                              hipStream_t stream) {
    const float* x   = (const float*)d_in[0];
    const int*   src = (const int*)d_in[1];
    const int*   dst = (const int*)d_in[2];
    const float* Ws1 = (const float*)d_in[3];
    const float* Wn1 = (const float*)d_in[4];
    const float* b1  = (const float*)d_in[5];
    const float* Ws2 = (const float*)d_in[6];
    const float* Wn2 = (const float*)d_in[7];
    const float* b2  = (const float*)d_in[8];
    const float* Ws3 = (const float*)d_in[9];
    const float* Wn3 = (const float*)d_in[10];
    const float* b3  = (const float*)d_in[11];

    unsigned short* H1  = (unsigned short*)d_ws;
    unsigned short* H2  = H1  + (size_t)MPAD * 512;
    unsigned short* T   = H2  + (size_t)MPAD * 512;
    unsigned short* Bt1 = T   + (size_t)MPAD * 128;
    unsigned short* Bt2 = Bt1 + 256 * 512;
    unsigned short* Bt3 = Bt2 + 256 * 512;
    float* b3ext = (float*)(Bt3 + 128 * 256);
    int* deg    = (int*)(b3ext + 128);
    int* cursor = deg + 102400;
    int* nbr    = cursor + 102400;

    // CSR build (graph shared by all layers); pad region zeroed for int4 scan.
    hipMemsetAsync(deg, 0, 102400 * sizeof(int), stream);
    degi_kernel<<<(NE + 255) / 256, 256, 0, stream>>>(dst, deg);
    scan_kernel<<<1, 1024, 0, stream>>>((const int4*)deg, (int4*)cursor);
    scatter_kernel<<<(NE + 255) / 256, 256, 0, stream>>>(src, dst, cursor, nbr);
    // cursor[d] = end offset; bucket d = nbr[end-deg .. end)

    // bf16 prep
    cast_x_kernel<<<(NN * 64 + 255) / 256, 256, 0, stream>>>((const float4*)x, H1);
    wprep_kernel<<<512, 256, 0, stream>>>(Ws1, Wn1, Bt1);
    wprep_kernel<<<512, 256, 0, stream>>>(Ws2, Wn2, Bt2);
    wprep3_kernel<<<128, 256, 0, stream>>>(Ws3, Wn3, b3, Bt3, b3ext);

    const int gatherBlocks = (NN + 3) / 4;
    const dim3 g2(MPAD / 128, 2), g1(MPAD / 128, 1);

    // layer 1: H1 -> H2(left)
    gather_bf16<<<gatherBlocks, 256, 0, stream>>>(H1, nbr, cursor, deg);
    sage_mfma<8, true><<<g2, 256, 0, stream>>>(H1, Bt1, b1, H2, 512);

    // layer 2: H2 -> H1(left)
    gather_bf16<<<gatherBlocks, 256, 0, stream>>>(H2, nbr, cursor, deg);
    sage_mfma<8, true><<<g2, 256, 0, stream>>>(H2, Bt2, b2, H1, 512);

    // layer 3: T = [H1@Ws3+b3 | H1@Wn3] (K=256), then out = S + agg(P)
    sage_mfma<4, false><<<g1, 256, 0, stream>>>(H1, Bt3, b3ext, T, 128);
    final_out<<<gatherBlocks, 256, 0, stream>>>(T, nbr, cursor, deg, (float*)d_out);
}

// Round 4
// 559.712 us; speedup vs baseline: 1.3544x; 1.0089x over previous
//
#include <hip/hip_runtime.h>

// GraphSAGE 3-layer inference — R9.
//  * R8's lane-parallel index prefetch, re-done through wave-local LDS instead
//    of defaulted-width __shfl (R8 failed: __shfl without explicit width=64 is
//    unsafe on gfx950 — lanes 32-63 pulled garbage). One coalesced load grabs
//    up to 64 neighbor ids into sidx[sub][lane]; rows read ids via uniform
//    ds_read broadcast (~120cy) instead of a ~600cy wave-uniform global load.
//    Removes the 2-deep dependent global-latency chain per 8-row round.
//  * GEMM (global_load_lds 2-phase double-buffer), CSR build, prep unchanged.

#define NN 100000
#define NE 800000
#define MPAD 100096   // 782 * 128

typedef __attribute__((ext_vector_type(8))) short short8;
typedef __attribute__((ext_vector_type(4))) float floatx4;

__device__ __forceinline__ float bf2f(unsigned short u) {
    unsigned int x = ((unsigned int)u) << 16;
    return __builtin_bit_cast(float, x);
}
__device__ __forceinline__ unsigned short f2bf(float f) {
    unsigned int x = __builtin_bit_cast(unsigned int, f);
    x += 0x7fffu + ((x >> 16) & 1u);   // round-to-nearest-even
    return (unsigned short)(x >> 16);
}

// async global->LDS, 16B per lane. LDS dest must be wave-uniform base; HW
// writes base + lane*16. Global src is per-lane.
__device__ __forceinline__ void gl_lds16(const unsigned short* g, unsigned short* l) {
    __builtin_amdgcn_global_load_lds(
        (const __attribute__((address_space(1))) unsigned int*)g,
        (__attribute__((address_space(3))) unsigned int*)l,
        16, 0, 0);
}

// ---------------- CSR build ----------------
__global__ void degi_kernel(const int* __restrict__ dst, int* __restrict__ deg) {
    int e = blockIdx.x * blockDim.x + threadIdx.x;
    if (e < NE) atomicAdd(&deg[dst[e]], 1);
}

// Exclusive scan of 102400 ints (int4 per thread, 25 iterations).
__global__ __launch_bounds__(1024) void scan_kernel(const int4* __restrict__ deg4,
                                                    int4* __restrict__ cur4) {
    __shared__ int wsum[16];
    __shared__ int carry_s;
    const int tid = threadIdx.x, lane = tid & 63, w = tid >> 6;
    if (tid == 0) carry_s = 0;
    __syncthreads();
    for (int base = 0; base < 25600; base += 1024) {
        int i = base + tid;
        int4 v = deg4[i];
        int t = v.x + v.y + v.z + v.w;
        int s = t;
        #pragma unroll
        for (int off = 1; off < 64; off <<= 1) {
            int u = __shfl_up(s, off, 64);
            if (lane >= off) s += u;
        }
        if (lane == 63) wsum[w] = s;
        __syncthreads();
        if (w == 0) {
            int ws_ = (lane < 16) ? wsum[lane] : 0;
            int t2 = ws_;
            #pragma unroll
            for (int off = 1; off < 16; off <<= 1) {
                int u = __shfl_up(t2, off, 64);
                if (lane >= off) t2 += u;
            }
            if (lane < 16) wsum[lane] = t2 - ws_;
        }
        __syncthreads();
        int excl = carry_s + wsum[w] + (s - t);
        int4 o;
        o.x = excl; o.y = o.x + v.x; o.z = o.y + v.y; o.w = o.z + v.z;
        cur4[i] = o;
        __syncthreads();
        if (tid == 1023) carry_s = excl + t;
        __syncthreads();
    }
}

__global__ void scatter_kernel(const int* __restrict__ src, const int* __restrict__ dst,
                               int* __restrict__ cursor, int* __restrict__ nbr) {
    int e = blockIdx.x * blockDim.x + threadIdx.x;
    if (e < NE) {
        int pos = atomicAdd(&cursor[dst[e]], 1);
        nbr[pos] = src[e];
    }
}

// ---------------- casts / weight prep ----------------
__global__ void cast_x_kernel(const float4* __restrict__ x, unsigned short* __restrict__ H) {
    int gid = blockIdx.x * 256 + threadIdx.x;   // NN*64 float4 groups
    if (gid >= NN * 64) return;
    int row = gid >> 6, col = (gid & 63) * 4;
    float4 v = x[gid];
    ushort4 o;
    o.x = f2bf(v.x); o.y = f2bf(v.y); o.z = f2bf(v.z); o.w = f2bf(v.w);
    *(ushort4*)&H[(size_t)row * 512 + col] = o;
}

// Bt[n][k] = bf16( k<256 ? Ws[k][n] : Wn[k-256][n] ),  [256][512]
__global__ void wprep_kernel(const float* __restrict__ Ws, const float* __restrict__ Wn,
                             unsigned short* __restrict__ Bt) {
    int idx = blockIdx.x * 256 + threadIdx.x;
    if (idx >= 256 * 512) return;
    int n = idx >> 9, k = idx & 511;
    float v = (k < 256) ? Ws[(size_t)k * 256 + n] : Wn[(size_t)(k - 256) * 256 + n];
    Bt[idx] = f2bf(v);
}

// Bt3[n][k] (n<128, k<256): n<64 -> Ws3[k][n], else Wn3[k][n-64]; b3ext = [b3 | 0]
__global__ void wprep3_kernel(const float* __restrict__ Ws3, const float* __restrict__ Wn3,
                              const float* __restrict__ b3, unsigned short* __restrict__ Bt3,
                              float* __restrict__ b3ext) {
    int idx = blockIdx.x * 256 + threadIdx.x;
    if (idx < 128 * 256) {
        int n = idx >> 8, k = idx & 255;
        float v = (n < 64) ? Ws3[(size_t)k * 64 + n] : Wn3[(size_t)k * 64 + (n - 64)];
        Bt3[idx] = f2bf(v);
    }
    if (idx < 128) b3ext[idx] = (idx < 64) ? b3[idx] : 0.f;
}

// ---------------- pull-mean gather: wave/node, LDS-prefetched indices ----------------
__global__ __launch_bounds__(256) void gather_bf16(unsigned short* __restrict__ H,
                                                   const int* __restrict__ nbr,
                                                   const int* __restrict__ cursor,
                                                   const int* __restrict__ deg) {
    __shared__ int sidx[4][64];
    const int lane = threadIdx.x & 63;
    const int sub  = threadIdx.x >> 6;
    const int d = blockIdx.x * 4 + sub;
    if (d >= NN) return;
    const int dg = deg[d];
    const int end = cursor[d];
    const int start = end - dg;
    const int co = lane * 4;          // shorts 4*lane .. +4 of the 256-short left half
    const int dgc = (dg < 64) ? dg : 64;

    // one coalesced 256B load grabs up to 64 neighbor indices; wave-local LDS
    // (single ds_write covers all lanes; compiler orders the dependent reads)
    if (lane < dgc) sidx[sub][lane] = nbr[start + lane];
    const int* si = sidx[sub];

    float acc[4] = {0.f, 0.f, 0.f, 0.f};

    int r = 0;
    for (; r + 8 <= dgc; r += 8) {     // 8 rows (4KB) in flight, no index latency
        int s0 = si[r + 0], s1 = si[r + 1], s2 = si[r + 2], s3 = si[r + 3];
        int s4 = si[r + 4], s5 = si[r + 5], s6 = si[r + 6], s7 = si[r + 7];
        ushort4 v0 = *(const ushort4*)&H[(size_t)s0 * 512 + co];
        ushort4 v1 = *(const ushort4*)&H[(size_t)s1 * 512 + co];
        ushort4 v2 = *(const ushort4*)&H[(size_t)s2 * 512 + co];
        ushort4 v3 = *(const ushort4*)&H[(size_t)s3 * 512 + co];
        ushort4 v4 = *(const ushort4*)&H[(size_t)s4 * 512 + co];
        ushort4 v5 = *(const ushort4*)&H[(size_t)s5 * 512 + co];
        ushort4 v6 = *(const ushort4*)&H[(size_t)s6 * 512 + co];
        ushort4 v7 = *(const ushort4*)&H[(size_t)s7 * 512 + co];
        acc[0] += (bf2f(v0.x) + bf2f(v1.x)) + (bf2f(v2.x) + bf2f(v3.x))
                + (bf2f(v4.x) + bf2f(v5.x)) + (bf2f(v6.x) + bf2f(v7.x));
        acc[1] += (bf2f(v0.y) + bf2f(v1.y)) + (bf2f(v2.y) + bf2f(v3.y))
                + (bf2f(v4.y) + bf2f(v5.y)) + (bf2f(v6.y) + bf2f(v7.y));
        acc[2] += (bf2f(v0.z) + bf2f(v1.z)) + (bf2f(v2.z) + bf2f(v3.z))
                + (bf2f(v4.z) + bf2f(v5.z)) + (bf2f(v6.z) + bf2f(v7.z));
        acc[3] += (bf2f(v0.w) + bf2f(v1.w)) + (bf2f(v2.w) + bf2f(v3.w))
                + (bf2f(v4.w) + bf2f(v5.w)) + (bf2f(v6.w) + bf2f(v7.w));
    }
    for (; r + 4 <= dgc; r += 4) {     // 4 rows in flight
        int s0 = si[r + 0], s1 = si[r + 1], s2 = si[r + 2], s3 = si[r + 3];
        ushort4 v0 = *(const ushort4*)&H[(size_t)s0 * 512 + co];
        ushort4 v1 = *(const ushort4*)&H[(size_t)s1 * 512 + co];
        ushort4 v2 = *(const ushort4*)&H[(size_t)s2 * 512 + co];
        ushort4 v3 = *(const ushort4*)&H[(size_t)s3 * 512 + co];
        acc[0] += (bf2f(v0.x) + bf2f(v1.x)) + (bf2f(v2.x) + bf2f(v3.x));
        acc[1] += (bf2f(v0.y) + bf2f(v1.y)) + (bf2f(v2.y) + bf2f(v3.y));
        acc[2] += (bf2f(v0.z) + bf2f(v1.z)) + (bf2f(v2.z) + bf2f(v3.z));
        acc[3] += (bf2f(v0.w) + bf2f(v1.w)) + (bf2f(v2.w) + bf2f(v3.w));
    }
    for (; r < dgc; ++r) {
        int s0 = si[r];
        ushort4 v0 = *(const ushort4*)&H[(size_t)s0 * 512 + co];
        acc[0] += bf2f(v0.x); acc[1] += bf2f(v0.y);
        acc[2] += bf2f(v0.z); acc[3] += bf2f(v0.w);
    }
    // deg > 64 tail (practically never for Poisson(8); kept for correctness)
    for (int j = start + 64; j < end; ++j) {
        int s0 = nbr[j];
        ushort4 v0 = *(const ushort4*)&H[(size_t)s0 * 512 + co];
        acc[0] += bf2f(v0.x); acc[1] += bf2f(v0.y);
        acc[2] += bf2f(v0.z); acc[3] += bf2f(v0.w);
    }

    const float inv = 1.0f / fmaxf((float)dg, 1.0f);
    ushort4 o;
    o.x = f2bf(acc[0] * inv); o.y = f2bf(acc[1] * inv);
    o.z = f2bf(acc[2] * inv); o.w = f2bf(acc[3] * inv);
    *(ushort4*)&H[(size_t)d * 512 + 256 + co] = o;
}

// ---------------- bf16 MFMA GEMM: global_load_lds double-buffered 2-phase ----------------
// C[128 x 128 per block] = A[., K] @ Bt^T + bias.
// A row stride 512 shorts (H fmt). Bt row stride = KT*64 shorts.
// KT = number of BK=64 K-steps (layer1/2: 8 -> K=512; layer3: 4 -> K=256).
template <int KT, bool RELU>
__global__ __launch_bounds__(256, 2) void sage_mfma(const unsigned short* __restrict__ A,
                                                    const unsigned short* __restrict__ Bt,
                                                    const float* __restrict__ bias,
                                                    unsigned short* __restrict__ Cout, int ldc) {
    __shared__ unsigned short sm[2][2][128 * 64];   // [buf][A=0/B=1][row*64+col], 64 KiB
    constexpr int BSTR = KT * 64;                   // Bt row stride in shorts
    const int tid = threadIdx.x;
    const int lane = tid & 63;
    const int w = tid >> 6, wm = w >> 1, wn = w & 1;
    const int m0 = blockIdx.x * 128, n0 = blockIdx.y * 128;
    const int lr = lane & 15, lq = lane >> 4;

    // staging geometry: wave w owns rows [w*32, w*32+32) of both tiles.
    const int srow = w * 32 + (lane >> 3);
    const int scol = (lane & 7) * 8;
    const unsigned short* gA = A  + (size_t)(m0 + srow) * 512  + scol;
    const unsigned short* gB = Bt + (size_t)(n0 + srow) * BSTR + scol;

    floatx4 acc[4][4] = {};

    // prologue: stage step 0 into buf 0
    {
        unsigned short* lA = &sm[0][0][(w * 32) * 64];
        unsigned short* lB = &sm[0][1][(w * 32) * 64];
        #pragma unroll
        for (int c = 0; c < 4; ++c) {
            gl_lds16(gA + (size_t)c * 8 * 512,  lA + c * 8 * 64);
            gl_lds16(gB + (size_t)c * 8 * BSTR, lB + c * 8 * 64);
        }
    }
    __syncthreads();

    #pragma unroll
    for (int t = 0; t < KT; ++t) {
        const int buf = t & 1;
        // phase 1: issue next step's DMA into the other buffer
        if (t + 1 < KT) {
            unsigned short* lA = &sm[buf ^ 1][0][(w * 32) * 64];
            unsigned short* lB = &sm[buf ^ 1][1][(w * 32) * 64];
            const unsigned short* pA = gA + (size_t)(t + 1) * 64;
            const unsigned short* pB = gB + (size_t)(t + 1) * 64;
            #pragma unroll
            for (int c = 0; c < 4; ++c) {
                gl_lds16(pA + (size_t)c * 8 * 512,  lA + c * 8 * 64);
                gl_lds16(pB + (size_t)c * 8 * BSTR, lB + c * 8 * 64);
            }
        }
        // phase 2: consume current buffer
        const unsigned short* bA = &sm[buf][0][0];
        const unsigned short* bB = &sm[buf][1][0];
        #pragma unroll
        for (int ks = 0; ks < 2; ++ks) {
            short8 af[4], bf[4];
            #pragma unroll
            for (int mi = 0; mi < 4; ++mi)
                af[mi] = *(const short8*)&bA[(wm * 64 + mi * 16 + lr) * 64 + ks * 32 + lq * 8];
            #pragma unroll
            for (int ni = 0; ni < 4; ++ni)
                bf[ni] = *(const short8*)&bB[(wn * 64 + ni * 16 + lr) * 64 + ks * 32 + lq * 8];
            #pragma unroll
            for (int mi = 0; mi < 4; ++mi)
                #pragma unroll
                for (int ni = 0; ni < 4; ++ni)
                    acc[mi][ni] = __builtin_amdgcn_mfma_f32_16x16x32_bf16(bf[ni], af[mi],
                                                                          acc[mi][ni], 0, 0, 0);
        }
        __syncthreads();   // drains this step's DMA (vmcnt) + all ds_reads
    }

    // Epilogue: bias + (relu) + bf16 -> LDS slab (aliases sm) -> coalesced 16B stores.
    unsigned short* slab = &sm[0][0][0];   // 128*136 shorts = 34816 B <= 64 KiB
    #pragma unroll
    for (int mi = 0; mi < 4; ++mi) {
        const int rl = wm * 64 + mi * 16 + lr;
        #pragma unroll
        for (int ni = 0; ni < 4; ++ni) {
            const int cl = wn * 64 + ni * 16 + lq * 4;
            const float4 bv = *(const float4*)&bias[n0 + cl];
            float v0 = acc[mi][ni][0] + bv.x;
            float v1 = acc[mi][ni][1] + bv.y;
            float v2 = acc[mi][ni][2] + bv.z;
            float v3 = acc[mi][ni][3] + bv.w;
            if (RELU) {
                v0 = fmaxf(v0, 0.f); v1 = fmaxf(v1, 0.f);
                v2 = fmaxf(v2, 0.f); v3 = fmaxf(v3, 0.f);
            }
            ushort4 o;
            o.x = f2bf(v0); o.y = f2bf(v1); o.z = f2bf(v2); o.w = f2bf(v3);
            *(ushort4*)&slab[rl * 136 + cl] = o;
        }
    }
    __syncthreads();
    #pragma unroll
    for (int it = 0; it < 8; ++it) {
        int idx = it * 256 + tid;
        int row = idx >> 4, c8 = (idx & 15) * 8;
        if (m0 + row < NN) {
            short8 v = *(const short8*)&slab[row * 136 + c8];
            *(short8*)&Cout[(size_t)(m0 + row) * ldc + n0 + c8] = v;
        }
    }
}

// ---------------- layer-3 finalize: out = S + mean_agg(P) ----------------
// 4 lane-groups x 16 lanes; group g handles rows r == g (mod 4); row ids come
// from the LDS-prefetched index vector. 2 rows in flight per group.
__global__ __launch_bounds__(256) void final_out(const unsigned short* __restrict__ T,
                                                 const int* __restrict__ nbr,
                                                 const int* __restrict__ cursor,
                                                 const int* __restrict__ deg,
                                                 float* __restrict__ out) {
    __shared__ int sidx[4][64];
    const int lane = threadIdx.x & 63;
    const int sub  = threadIdx.x >> 6;
    const int d = blockIdx.x * 4 + sub;
    if (d >= NN) return;
    const int g  = lane >> 4;         // edge group 0..3
    const int li = lane & 15;         // column li*4 .. +4
    const int dg = deg[d];
    const int end = cursor[d];
    const int start = end - dg;
    const int co = li * 4;
    const int dgc = (dg < 64) ? dg : 64;

    // self row (same addresses in all 4 groups -> broadcast), issued early
    ushort4 sv = *(const ushort4*)&T[(size_t)d * 128 + co];

    // one coalesced load grabs up to 64 neighbor indices into wave-local LDS
    if (lane < dgc) sidx[sub][lane] = nbr[start + lane];
    const int* si = sidx[sub];

    float acc[4] = {0.f, 0.f, 0.f, 0.f};
    int r = g;
    for (; r + 4 < dgc; r += 8) {     // 2 rows/group (8/wave) in flight
        int s0 = si[r], s1 = si[r + 4];
        ushort4 v0 = *(const ushort4*)&T[(size_t)s0 * 128 + 64 + co];
        ushort4 v1 = *(const ushort4*)&T[(size_t)s1 * 128 + 64 + co];
        acc[0] += bf2f(v0.x) + bf2f(v1.x);
        acc[1] += bf2f(v0.y) + bf2f(v1.y);
        acc[2] += bf2f(v0.z) + bf2f(v1.z);
        acc[3] += bf2f(v0.w) + bf2f(v1.w);
    }
    for (; r < dgc; r += 4) {
        int s0 = si[r];
        ushort4 v0 = *(const ushort4*)&T[(size_t)s0 * 128 + 64 + co];
        acc[0] += bf2f(v0.x); acc[1] += bf2f(v0.y);
        acc[2] += bf2f(v0.z); acc[3] += bf2f(v0.w);
    }
    // deg > 64 tail (practically never; row i>=64 belongs to group i%4 == g)
    for (int j = start + 64 + g; j < end; j += 4) {
        int s0 = nbr[j];
        ushort4 v0 = *(const ushort4*)&T[(size_t)s0 * 128 + 64 + co];
        acc[0] += bf2f(v0.x); acc[1] += bf2f(v0.y);
        acc[2] += bf2f(v0.z); acc[3] += bf2f(v0.w);
    }

    // combine the 4 groups: lanes differing in bits 4/5 hold same columns
    #pragma unroll
    for (int i = 0; i < 4; ++i) {
        acc[i] += __shfl_xor(acc[i], 16, 64);
        acc[i] += __shfl_xor(acc[i], 32, 64);
    }

    if (g == 0) {
        const float inv = 1.0f / fmaxf((float)dg, 1.0f);
        float4 o;
        o.x = bf2f(sv.x) + acc[0] * inv;
        o.y = bf2f(sv.y) + acc[1] * inv;
        o.z = bf2f(sv.z) + acc[2] * inv;
        o.w = bf2f(sv.w) + acc[3] * inv;
        *(float4*)&out[(size_t)d * 64 + co] = o;
    }
}

extern "C" void kernel_launch(void* const* d_in, const int* in_sizes, int n_in,
                              void* d_out, int out_size, void* d_ws, size_t ws_size,
                              hipStream_t stream) {
    const float* x   = (const float*)d_in[0];
    const int*   src = (const int*)d_in[1];
    const int*   dst = (const int*)d_in[2];
    const float* Ws1 = (const float*)d_in[3];
    const float* Wn1 = (const float*)d_in[4];
    const float* b1  = (const float*)d_in[5];
    const float* Ws2 = (const float*)d_in[6];
    const float* Wn2 = (const float*)d_in[7];
    const float* b2  = (const float*)d_in[8];
    const float* Ws3 = (const float*)d_in[9];
    const float* Wn3 = (const float*)d_in[10];
    const float* b3  = (const float*)d_in[11];

    unsigned short* H1  = (unsigned short*)d_ws;
    unsigned short* H2  = H1  + (size_t)MPAD * 512;
    unsigned short* T   = H2  + (size_t)MPAD * 512;
    unsigned short* Bt1 = T   + (size_t)MPAD * 128;
    unsigned short* Bt2 = Bt1 + 256 * 512;
    unsigned short* Bt3 = Bt2 + 256 * 512;
    float* b3ext = (float*)(Bt3 + 128 * 256);
    int* deg    = (int*)(b3ext + 128);
    int* cursor = deg + 102400;
    int* nbr    = cursor + 102400;

    // CSR build (graph shared by all layers); pad region zeroed for int4 scan.
    hipMemsetAsync(deg, 0, 102400 * sizeof(int), stream);
    degi_kernel<<<(NE + 255) / 256, 256, 0, stream>>>(dst, deg);
    scan_kernel<<<1, 1024, 0, stream>>>((const int4*)deg, (int4*)cursor);
    scatter_kernel<<<(NE + 255) / 256, 256, 0, stream>>>(src, dst, cursor, nbr);
    // cursor[d] = end offset; bucket d = nbr[end-deg .. end)

    // bf16 prep
    cast_x_kernel<<<(NN * 64 + 255) / 256, 256, 0, stream>>>((const float4*)x, H1);
    wprep_kernel<<<512, 256, 0, stream>>>(Ws1, Wn1, Bt1);
    wprep_kernel<<<512, 256, 0, stream>>>(Ws2, Wn2, Bt2);
    wprep3_kernel<<<128, 256, 0, stream>>>(Ws3, Wn3, b3, Bt3, b3ext);

    const int gatherBlocks = (NN + 3) / 4;
    const dim3 g2(MPAD / 128, 2), g1(MPAD / 128, 1);

    // layer 1: H1 -> H2(left)
    gather_bf16<<<gatherBlocks, 256, 0, stream>>>(H1, nbr, cursor, deg);
    sage_mfma<8, true><<<g2, 256, 0, stream>>>(H1, Bt1, b1, H2, 512);

    // layer 2: H2 -> H1(left)
    gather_bf16<<<gatherBlocks, 256, 0, stream>>>(H2, nbr, cursor, deg);
    sage_mfma<8, true><<<g2, 256, 0, stream>>>(H2, Bt2, b2, H1, 512);

    // layer 3: T = [H1@Ws3+b3 | H1@Wn3] (K=256), then out = S + agg(P)
    sage_mfma<4, false><<<g1, 256, 0, stream>>>(H1, Bt3, b3ext, T, 128);
    final_out<<<gatherBlocks, 256, 0, stream>>>(T, nbr, cursor, deg, (float*)d_out);
}

// Round 5
// 533.334 us; speedup vs baseline: 1.4213x; 1.0495x over previous
//
#include <hip/hip_runtime.h>

// GraphSAGE 3-layer inference — R10.
//  * scan: replaced single-block 25-iteration scan (one CU busy ~30us) with a
//    3-pass multi-block scan (100 blocks local scan -> 1-wave scan of 100
//    block sums -> offset add). ~6-8us total.
//  * GEMM: BK=32 double-buffer -> LDS 34.8KB -> 4 blocks/CU (overlaps the
//    2-phase barrier/vmcnt drain across blocks), plus a 2-bit slot-XOR LDS
//    swizzle (pre-swizzled global source for global_load_lds + swizzled
//    ds_read, rule both-sides-or-neither) cutting the 16-way ds_read_b128
//    bank conflict of the 128B-row-stride tile to 4-way.
//  * gather/final_out (throughput-limited per R9 counters), CSR build, prep
//    unchanged.

#define NN 100000
#define NE 800000
#define MPAD 100096   // 782 * 128

typedef __attribute__((ext_vector_type(8))) short short8;
typedef __attribute__((ext_vector_type(4))) float floatx4;

__device__ __forceinline__ float bf2f(unsigned short u) {
    unsigned int x = ((unsigned int)u) << 16;
    return __builtin_bit_cast(float, x);
}
__device__ __forceinline__ unsigned short f2bf(float f) {
    unsigned int x = __builtin_bit_cast(unsigned int, f);
    x += 0x7fffu + ((x >> 16) & 1u);   // round-to-nearest-even
    return (unsigned short)(x >> 16);
}

// async global->LDS, 16B per lane. LDS dest must be wave-uniform base; HW
// writes base + lane*16. Global src is per-lane.
__device__ __forceinline__ void gl_lds16(const unsigned short* g, unsigned short* l) {
    __builtin_amdgcn_global_load_lds(
        (const __attribute__((address_space(1))) unsigned int*)g,
        (__attribute__((address_space(3))) unsigned int*)l,
        16, 0, 0);
}

// ---------------- CSR build ----------------
__global__ void degi_kernel(const int* __restrict__ dst, int* __restrict__ deg) {
    int e = blockIdx.x * blockDim.x + threadIdx.x;
    if (e < NE) atomicAdd(&deg[dst[e]], 1);
}

// 3-pass exclusive scan of 102400 ints (25600 int4).
// scan1: 100 blocks x 256 thr, block-local exclusive scan + block sum.
__global__ __launch_bounds__(256) void scan1(const int4* __restrict__ deg4,
                                             int4* __restrict__ cur4,
                                             int* __restrict__ bsum) {
    __shared__ int woff[4];
    const int tid = threadIdx.x, lane = tid & 63, w = tid >> 6;
    const int i = blockIdx.x * 256 + tid;
    int4 v = deg4[i];
    int t = v.x + v.y + v.z + v.w;
    int s = t;
    #pragma unroll
    for (int off = 1; off < 64; off <<= 1) {
        int u = __shfl_up(s, off, 64);
        if (lane >= off) s += u;
    }
    if (lane == 63) woff[w] = s;
    __syncthreads();
    if (tid == 0) {
        int a0 = woff[0], a1 = woff[1], a2 = woff[2], a3 = woff[3];
        woff[0] = 0; woff[1] = a0; woff[2] = a0 + a1; woff[3] = a0 + a1 + a2;
        bsum[blockIdx.x] = a0 + a1 + a2 + a3;
    }
    __syncthreads();
    int excl = woff[w] + (s - t);
    int4 o;
    o.x = excl; o.y = o.x + v.x; o.z = o.y + v.y; o.w = o.z + v.z;
    cur4[i] = o;
}

// scan2: single wave, in-place exclusive scan of bsum[100].
__global__ void scan2(int* __restrict__ bsum) {
    const int lane = threadIdx.x;   // 64 threads
    int carry = 0;
    for (int base = 0; base < 100; base += 64) {
        int n = 100 - base; if (n > 64) n = 64;
        int v = (lane < n) ? bsum[base + lane] : 0;
        int s = v;
        #pragma unroll
        for (int off = 1; off < 64; off <<= 1) {
            int u = __shfl_up(s, off, 64);
            if (lane >= off) s += u;
        }
        int tot = __shfl(s, 63, 64);
        if (lane < n) bsum[base + lane] = carry + s - v;
        carry += tot;
    }
}

// scan3: add block offsets.
__global__ __launch_bounds__(256) void scan3(int4* __restrict__ cur4,
                                             const int* __restrict__ bsum) {
    const int i = blockIdx.x * 256 + threadIdx.x;
    const int o = bsum[blockIdx.x];
    int4 v = cur4[i];
    v.x += o; v.y += o; v.z += o; v.w += o;
    cur4[i] = v;
}

__global__ void scatter_kernel(const int* __restrict__ src, const int* __restrict__ dst,
                               int* __restrict__ cursor, int* __restrict__ nbr) {
    int e = blockIdx.x * blockDim.x + threadIdx.x;
    if (e < NE) {
        int pos = atomicAdd(&cursor[dst[e]], 1);
        nbr[pos] = src[e];
    }
}

// ---------------- casts / weight prep ----------------
__global__ void cast_x_kernel(const float4* __restrict__ x, unsigned short* __restrict__ H) {
    int gid = blockIdx.x * 256 + threadIdx.x;   // NN*64 float4 groups
    if (gid >= NN * 64) return;
    int row = gid >> 6, col = (gid & 63) * 4;
    float4 v = x[gid];
    ushort4 o;
    o.x = f2bf(v.x); o.y = f2bf(v.y); o.z = f2bf(v.z); o.w = f2bf(v.w);
    *(ushort4*)&H[(size_t)row * 512 + col] = o;
}

// Bt[n][k] = bf16( k<256 ? Ws[k][n] : Wn[k-256][n] ),  [256][512]
__global__ void wprep_kernel(const float* __restrict__ Ws, const float* __restrict__ Wn,
                             unsigned short* __restrict__ Bt) {
    int idx = blockIdx.x * 256 + threadIdx.x;
    if (idx >= 256 * 512) return;
    int n = idx >> 9, k = idx & 511;
    float v = (k < 256) ? Ws[(size_t)k * 256 + n] : Wn[(size_t)(k - 256) * 256 + n];
    Bt[idx] = f2bf(v);
}

// Bt3[n][k] (n<128, k<256): n<64 -> Ws3[k][n], else Wn3[k][n-64]; b3ext = [b3 | 0]
__global__ void wprep3_kernel(const float* __restrict__ Ws3, const float* __restrict__ Wn3,
                              const float* __restrict__ b3, unsigned short* __restrict__ Bt3,
                              float* __restrict__ b3ext) {
    int idx = blockIdx.x * 256 + threadIdx.x;
    if (idx < 128 * 256) {
        int n = idx >> 8, k = idx & 255;
        float v = (n < 64) ? Ws3[(size_t)k * 64 + n] : Wn3[(size_t)k * 64 + (n - 64)];
        Bt3[idx] = f2bf(v);
    }
    if (idx < 128) b3ext[idx] = (idx < 64) ? b3[idx] : 0.f;
}

// ---------------- pull-mean gather: wave/node, LDS-prefetched indices ----------------
__global__ __launch_bounds__(256) void gather_bf16(unsigned short* __restrict__ H,
                                                   const int* __restrict__ nbr,
                                                   const int* __restrict__ cursor,
                                                   const int* __restrict__ deg) {
    __shared__ int sidx[4][64];
    const int lane = threadIdx.x & 63;
    const int sub  = threadIdx.x >> 6;
    const int d = blockIdx.x * 4 + sub;
    if (d >= NN) return;
    const int dg = deg[d];
    const int end = cursor[d];
    const int start = end - dg;
    const int co = lane * 4;          // shorts 4*lane .. +4 of the 256-short left half
    const int dgc = (dg < 64) ? dg : 64;

    if (lane < dgc) sidx[sub][lane] = nbr[start + lane];
    const int* si = sidx[sub];

    float acc[4] = {0.f, 0.f, 0.f, 0.f};

    int r = 0;
    for (; r + 8 <= dgc; r += 8) {     // 8 rows (4KB) in flight
        int s0 = si[r + 0], s1 = si[r + 1], s2 = si[r + 2], s3 = si[r + 3];
        int s4 = si[r + 4], s5 = si[r + 5], s6 = si[r + 6], s7 = si[r + 7];
        ushort4 v0 = *(const ushort4*)&H[(size_t)s0 * 512 + co];
        ushort4 v1 = *(const ushort4*)&H[(size_t)s1 * 512 + co];
        ushort4 v2 = *(const ushort4*)&H[(size_t)s2 * 512 + co];
        ushort4 v3 = *(const ushort4*)&H[(size_t)s3 * 512 + co];
        ushort4 v4 = *(const ushort4*)&H[(size_t)s4 * 512 + co];
        ushort4 v5 = *(const ushort4*)&H[(size_t)s5 * 512 + co];
        ushort4 v6 = *(const ushort4*)&H[(size_t)s6 * 512 + co];
        ushort4 v7 = *(const ushort4*)&H[(size_t)s7 * 512 + co];
        acc[0] += (bf2f(v0.x) + bf2f(v1.x)) + (bf2f(v2.x) + bf2f(v3.x))
                + (bf2f(v4.x) + bf2f(v5.x)) + (bf2f(v6.x) + bf2f(v7.x));
        acc[1] += (bf2f(v0.y) + bf2f(v1.y)) + (bf2f(v2.y) + bf2f(v3.y))
                + (bf2f(v4.y) + bf2f(v5.y)) + (bf2f(v6.y) + bf2f(v7.y));
        acc[2] += (bf2f(v0.z) + bf2f(v1.z)) + (bf2f(v2.z) + bf2f(v3.z))
                + (bf2f(v4.z) + bf2f(v5.z)) + (bf2f(v6.z) + bf2f(v7.z));
        acc[3] += (bf2f(v0.w) + bf2f(v1.w)) + (bf2f(v2.w) + bf2f(v3.w))
                + (bf2f(v4.w) + bf2f(v5.w)) + (bf2f(v6.w) + bf2f(v7.w));
    }
    for (; r + 4 <= dgc; r += 4) {
        int s0 = si[r + 0], s1 = si[r + 1], s2 = si[r + 2], s3 = si[r + 3];
        ushort4 v0 = *(const ushort4*)&H[(size_t)s0 * 512 + co];
        ushort4 v1 = *(const ushort4*)&H[(size_t)s1 * 512 + co];
        ushort4 v2 = *(const ushort4*)&H[(size_t)s2 * 512 + co];
        ushort4 v3 = *(const ushort4*)&H[(size_t)s3 * 512 + co];
        acc[0] += (bf2f(v0.x) + bf2f(v1.x)) + (bf2f(v2.x) + bf2f(v3.x));
        acc[1] += (bf2f(v0.y) + bf2f(v1.y)) + (bf2f(v2.y) + bf2f(v3.y));
        acc[2] += (bf2f(v0.z) + bf2f(v1.z)) + (bf2f(v2.z) + bf2f(v3.z));
        acc[3] += (bf2f(v0.w) + bf2f(v1.w)) + (bf2f(v2.w) + bf2f(v3.w));
    }
    for (; r < dgc; ++r) {
        int s0 = si[r];
        ushort4 v0 = *(const ushort4*)&H[(size_t)s0 * 512 + co];
        acc[0] += bf2f(v0.x); acc[1] += bf2f(v0.y);
        acc[2] += bf2f(v0.z); acc[3] += bf2f(v0.w);
    }
    for (int j = start + 64; j < end; ++j) {   // deg>64 tail (practically never)
        int s0 = nbr[j];
        ushort4 v0 = *(const ushort4*)&H[(size_t)s0 * 512 + co];
        acc[0] += bf2f(v0.x); acc[1] += bf2f(v0.y);
        acc[2] += bf2f(v0.z); acc[3] += bf2f(v0.w);
    }

    const float inv = 1.0f / fmaxf((float)dg, 1.0f);
    ushort4 o;
    o.x = f2bf(acc[0] * inv); o.y = f2bf(acc[1] * inv);
    o.z = f2bf(acc[2] * inv); o.w = f2bf(acc[3] * inv);
    *(ushort4*)&H[(size_t)d * 512 + 256 + co] = o;
}

// ---------------- bf16 MFMA GEMM: BK=32 dbuf, 4 blocks/CU, slot-XOR swizzle ----------------
// C[128 x 128 per block] = A[., K] @ Bt^T + bias. KT = K/32.
// LDS tile [128][32] shorts (64B rows). Slot-XOR: LDS[row][slot] holds
// global[row][slot ^ (row&3)] (16B slots); applied on the global SOURCE of
// global_load_lds and on the ds_read address -> 16-way conflict becomes 4-way.
template <int KT, bool RELU>
__global__ __launch_bounds__(256, 4) void sage_mfma(const unsigned short* __restrict__ A,
                                                    const unsigned short* __restrict__ Bt,
                                                    const float* __restrict__ bias,
                                                    unsigned short* __restrict__ Cout, int ldc) {
    __shared__ unsigned short lds[17408];   // 34816 B: dbuf 2x2x4096 shorts; slab 17408
    constexpr int BSTR = KT * 32;           // Bt row stride in shorts
    const int tid = threadIdx.x;
    const int lane = tid & 63;
    const int w = tid >> 6, wm = w >> 1, wn = w & 1;
    const int m0 = blockIdx.x * 128, n0 = blockIdx.y * 128;
    const int lr = lane & 15, lq = lane >> 4;

    // staging: wave w owns rows [w*32, w*32+32); lane l covers row +(l>>2),
    // slot (l&3). Source column pre-swizzled: slot ^ (row&3).
    const int sr   = lane >> 2;                       // 0..15 within 16-row chunk
    const int ssl  = (lane & 3) ^ (sr & 3);           // swizzled source slot
    const unsigned short* gA = A  + (size_t)(m0 + w * 32 + sr) * 512  + ssl * 8;
    const unsigned short* gB = Bt + (size_t)(n0 + w * 32 + sr) * BSTR + ssl * 8;

    // read-side swizzled slot offset (shorts): (lq ^ (lr&3)) * 8
    const int lqx = (lq ^ (lr & 3)) * 8;

    floatx4 acc[4][4] = {};

    // prologue: stage step 0 into buf 0
    {
        unsigned short* lA = &lds[0 * 8192 + (w * 32) * 32];
        unsigned short* lB = &lds[0 * 8192 + 4096 + (w * 32) * 32];
        #pragma unroll
        for (int c = 0; c < 2; ++c) {
            gl_lds16(gA + (size_t)c * 16 * 512,  lA + c * 512);
            gl_lds16(gB + (size_t)c * 16 * BSTR, lB + c * 512);
        }
    }
    __syncthreads();

    #pragma unroll
    for (int t = 0; t < KT; ++t) {
        const int buf = t & 1;
        if (t + 1 < KT) {
            unsigned short* lA = &lds[(buf ^ 1) * 8192 + (w * 32) * 32];
            unsigned short* lB = &lds[(buf ^ 1) * 8192 + 4096 + (w * 32) * 32];
            const unsigned short* pA = gA + (size_t)(t + 1) * 32;
            const unsigned short* pB = gB + (size_t)(t + 1) * 32;
            #pragma unroll
            for (int c = 0; c < 2; ++c) {
                gl_lds16(pA + (size_t)c * 16 * 512,  lA + c * 512);
                gl_lds16(pB + (size_t)c * 16 * BSTR, lB + c * 512);
            }
        }
        const unsigned short* bA = &lds[buf * 8192];
        const unsigned short* bB = bA + 4096;
        short8 af[4], bf[4];
        #pragma unroll
        for (int mi = 0; mi < 4; ++mi)
            af[mi] = *(const short8*)&bA[(wm * 64 + mi * 16 + lr) * 32 + lqx];
        #pragma unroll
        for (int ni = 0; ni < 4; ++ni)
            bf[ni] = *(const short8*)&bB[(wn * 64 + ni * 16 + lr) * 32 + lqx];
        #pragma unroll
        for (int mi = 0; mi < 4; ++mi)
            #pragma unroll
            for (int ni = 0; ni < 4; ++ni)
                acc[mi][ni] = __builtin_amdgcn_mfma_f32_16x16x32_bf16(bf[ni], af[mi],
                                                                      acc[mi][ni], 0, 0, 0);
        __syncthreads();   // drains this step's DMA (vmcnt) + all ds_reads
    }

    // Epilogue: bias + (relu) + bf16 -> LDS slab -> coalesced 16B stores.
    unsigned short* slab = &lds[0];   // 128*136 shorts = 17408
    #pragma unroll
    for (int mi = 0; mi < 4; ++mi) {
        const int rl = wm * 64 + mi * 16 + lr;
        #pragma unroll
        for (int ni = 0; ni < 4; ++ni) {
            const int cl = wn * 64 + ni * 16 + lq * 4;
            const float4 bv = *(const float4*)&bias[n0 + cl];
            float v0 = acc[mi][ni][0] + bv.x;
            float v1 = acc[mi][ni][1] + bv.y;
            float v2 = acc[mi][ni][2] + bv.z;
            float v3 = acc[mi][ni][3] + bv.w;
            if (RELU) {
                v0 = fmaxf(v0, 0.f); v1 = fmaxf(v1, 0.f);
                v2 = fmaxf(v2, 0.f); v3 = fmaxf(v3, 0.f);
            }
            ushort4 o;
            o.x = f2bf(v0); o.y = f2bf(v1); o.z = f2bf(v2); o.w = f2bf(v3);
            *(ushort4*)&slab[rl * 136 + cl] = o;
        }
    }
    __syncthreads();
    #pragma unroll
    for (int it = 0; it < 8; ++it) {
        int idx = it * 256 + tid;
        int row = idx >> 4, c8 = (idx & 15) * 8;
        if (m0 + row < NN) {
            short8 v = *(const short8*)&slab[row * 136 + c8];
            *(short8*)&Cout[(size_t)(m0 + row) * ldc + n0 + c8] = v;
        }
    }
}

// ---------------- layer-3 finalize: out = S + mean_agg(P) ----------------
__global__ __launch_bounds__(256) void final_out(const unsigned short* __restrict__ T,
                                                 const int* __restrict__ nbr,
                                                 const int* __restrict__ cursor,
                                                 const int* __restrict__ deg,
                                                 float* __restrict__ out) {
    __shared__ int sidx[4][64];
    const int lane = threadIdx.x & 63;
    const int sub  = threadIdx.x >> 6;
    const int d = blockIdx.x * 4 + sub;
    if (d >= NN) return;
    const int g  = lane >> 4;         // edge group 0..3
    const int li = lane & 15;         // column li*4 .. +4
    const int dg = deg[d];
    const int end = cursor[d];
    const int start = end - dg;
    const int co = li * 4;
    const int dgc = (dg < 64) ? dg : 64;

    ushort4 sv = *(const ushort4*)&T[(size_t)d * 128 + co];

    if (lane < dgc) sidx[sub][lane] = nbr[start + lane];
    const int* si = sidx[sub];

    float acc[4] = {0.f, 0.f, 0.f, 0.f};
    int r = g;
    for (; r + 4 < dgc; r += 8) {
        int s0 = si[r], s1 = si[r + 4];
        ushort4 v0 = *(const ushort4*)&T[(size_t)s0 * 128 + 64 + co];
        ushort4 v1 = *(const ushort4*)&T[(size_t)s1 * 128 + 64 + co];
        acc[0] += bf2f(v0.x) + bf2f(v1.x);
        acc[1] += bf2f(v0.y) + bf2f(v1.y);
        acc[2] += bf2f(v0.z) + bf2f(v1.z);
        acc[3] += bf2f(v0.w) + bf2f(v1.w);
    }
    for (; r < dgc; r += 4) {
        int s0 = si[r];
        ushort4 v0 = *(const ushort4*)&T[(size_t)s0 * 128 + 64 + co];
        acc[0] += bf2f(v0.x); acc[1] += bf2f(v0.y);
        acc[2] += bf2f(v0.z); acc[3] += bf2f(v0.w);
    }
    for (int j = start + 64 + g; j < end; j += 4) {   // deg>64 tail
        int s0 = nbr[j];
        ushort4 v0 = *(const ushort4*)&T[(size_t)s0 * 128 + 64 + co];
        acc[0] += bf2f(v0.x); acc[1] += bf2f(v0.y);
        acc[2] += bf2f(v0.z); acc[3] += bf2f(v0.w);
    }

    #pragma unroll
    for (int i = 0; i < 4; ++i) {
        acc[i] += __shfl_xor(acc[i], 16, 64);
        acc[i] += __shfl_xor(acc[i], 32, 64);
    }

    if (g == 0) {
        const float inv = 1.0f / fmaxf((float)dg, 1.0f);
        float4 o;
        o.x = bf2f(sv.x) + acc[0] * inv;
        o.y = bf2f(sv.y) + acc[1] * inv;
        o.z = bf2f(sv.z) + acc[2] * inv;
        o.w = bf2f(sv.w) + acc[3] * inv;
        *(float4*)&out[(size_t)d * 64 + co] = o;
    }
}

extern "C" void kernel_launch(void* const* d_in, const int* in_sizes, int n_in,
                              void* d_out, int out_size, void* d_ws, size_t ws_size,
                              hipStream_t stream) {
    const float* x   = (const float*)d_in[0];
    const int*   src = (const int*)d_in[1];
    const int*   dst = (const int*)d_in[2];
    const float* Ws1 = (const float*)d_in[3];
    const float* Wn1 = (const float*)d_in[4];
    const float* b1  = (const float*)d_in[5];
    const float* Ws2 = (const float*)d_in[6];
    const float* Wn2 = (const float*)d_in[7];
    const float* b2  = (const float*)d_in[8];
    const float* Ws3 = (const float*)d_in[9];
    const float* Wn3 = (const float*)d_in[10];
    const float* b3  = (const float*)d_in[11];

    unsigned short* H1  = (unsigned short*)d_ws;
    unsigned short* H2  = H1  + (size_t)MPAD * 512;
    unsigned short* T   = H2  + (size_t)MPAD * 512;
    unsigned short* Bt1 = T   + (size_t)MPAD * 128;
    unsigned short* Bt2 = Bt1 + 256 * 512;
    unsigned short* Bt3 = Bt2 + 256 * 512;
    float* b3ext = (float*)(Bt3 + 128 * 256);
    int* deg    = (int*)(b3ext + 128);
    int* cursor = deg + 102400;
    int* nbr    = cursor + 102400;
    int* bsum   = nbr + NE;           // 100 ints (+pad)

    // CSR build (graph shared by all layers); pad region zeroed for int4 scan.
    hipMemsetAsync(deg, 0, 102400 * sizeof(int), stream);
    degi_kernel<<<(NE + 255) / 256, 256, 0, stream>>>(dst, deg);
    scan1<<<100, 256, 0, stream>>>((const int4*)deg, (int4*)cursor, bsum);
    scan2<<<1, 64, 0, stream>>>(bsum);
    scan3<<<100, 256, 0, stream>>>((int4*)cursor, bsum);
    scatter_kernel<<<(NE + 255) / 256, 256, 0, stream>>>(src, dst, cursor, nbr);
    // cursor[d] = end offset; bucket d = nbr[end-deg .. end)

    // bf16 prep
    cast_x_kernel<<<(NN * 64 + 255) / 256, 256, 0, stream>>>((const float4*)x, H1);
    wprep_kernel<<<512, 256, 0, stream>>>(Ws1, Wn1, Bt1);
    wprep_kernel<<<512, 256, 0, stream>>>(Ws2, Wn2, Bt2);
    wprep3_kernel<<<128, 256, 0, stream>>>(Ws3, Wn3, b3, Bt3, b3ext);

    const int gatherBlocks = (NN + 3) / 4;
    const dim3 g2(MPAD / 128, 2), g1(MPAD / 128, 1);

    // layer 1: H1 -> H2(left)
    gather_bf16<<<gatherBlocks, 256, 0, stream>>>(H1, nbr, cursor, deg);
    sage_mfma<16, true><<<g2, 256, 0, stream>>>(H1, Bt1, b1, H2, 512);

    // layer 2: H2 -> H1(left)
    gather_bf16<<<gatherBlocks, 256, 0, stream>>>(H2, nbr, cursor, deg);
    sage_mfma<16, true><<<g2, 256, 0, stream>>>(H2, Bt2, b2, H1, 512);

    // layer 3: T = [H1@Ws3+b3 | H1@Wn3] (K=256), then out = S + agg(P)
    sage_mfma<8, false><<<g1, 256, 0, stream>>>(H1, Bt3, b3ext, T, 128);
    final_out<<<gatherBlocks, 256, 0, stream>>>(T, nbr, cursor, deg, (float*)d_out);
}